// Round 7
// baseline (55.774 us; speedup 1.0000x reference)
//
#include <hip/hip_runtime.h>
#include <hip/hip_bf16.h>

using bf16x8 = __attribute__((ext_vector_type(8))) short;
using f32x4  = __attribute__((ext_vector_type(4))) float;
using f32x16 = __attribute__((ext_vector_type(16))) float;
using u32x4  = __attribute__((ext_vector_type(4))) unsigned;

constexpr int N_ = 512;
constexpr int C_ = 32;
constexpr int NTILES = 2 * N_ * (N_ / 32);   // 16384 tile-jobs

__device__ __forceinline__ unsigned pkbf(float lo, float hi) {
    unsigned a = (unsigned short)__builtin_bit_cast(short, __float2bfloat16(lo));
    unsigned b = (unsigned short)__builtin_bit_cast(short, __float2bfloat16(hi));
    return a | (b << 16);
}

// One 32-edge tile per wave. 16384 waves total -> TLP hides all load latency.
// Within-tile math identical to the R6-proven kernel (layouts validated).
template <bool USE_WS>
__global__ __launch_bounds__(256, 4)
void filter_tile(const float* __restrict__ tensor,  // [B,N,C,3]
                 const float* __restrict__ rbf,     // [B,N,N,32]
                 const float* __restrict__ rij,     // [B,N,N,3]
                 const float* __restrict__ W1,
                 const float* __restrict__ b1,
                 const float* __restrict__ W2,
                 const float* __restrict__ b2,
                 float* __restrict__ dst)  // USE_WS: ws[NTILES][32]; else out[B*N*32] (atomic)
{
    const int tid  = threadIdx.x;
    const int lane = tid & 63;
    const int w    = tid >> 6;
    const int l    = lane & 31;   // edge-in-tile / A-row / C-col
    const int l5   = lane >> 5;   // k-group (0,1)

    const int T  = blockIdx.x * 4 + w;   // tile id
    const int bn = T >> 4;
    const int b  = bn >> 9;
    const int e0 = (T & 15) * 32;
    const int k  = e0 + l;               // this lane's edge

    // Weight A-fragments: lane holds row m=l, k = 8*l5+e (frag0), 16+8*l5+e (frag1)
    bf16x8 W1a[2], W2a[2];
    {
        const float* p1 = W1 + l * 32 + 8 * l5;
        const float* p2 = W2 + l * 32 + 8 * l5;
        const f32x4 a0 = ((const f32x4*)p1)[0], a1 = ((const f32x4*)p1)[1];
        const f32x4 a2 = ((const f32x4*)(p1 + 16))[0], a3 = ((const f32x4*)(p1 + 16))[1];
        const f32x4 c0 = ((const f32x4*)p2)[0], c1 = ((const f32x4*)p2)[1];
        const f32x4 c2 = ((const f32x4*)(p2 + 16))[0], c3 = ((const f32x4*)(p2 + 16))[1];
        #pragma unroll
        for (int e = 0; e < 4; ++e) {
            W1a[0][e] = __builtin_bit_cast(short, __float2bfloat16(a0[e]));
            W1a[0][4 + e] = __builtin_bit_cast(short, __float2bfloat16(a1[e]));
            W1a[1][e] = __builtin_bit_cast(short, __float2bfloat16(a2[e]));
            W1a[1][4 + e] = __builtin_bit_cast(short, __float2bfloat16(a3[e]));
            W2a[0][e] = __builtin_bit_cast(short, __float2bfloat16(c0[e]));
            W2a[0][4 + e] = __builtin_bit_cast(short, __float2bfloat16(c1[e]));
            W2a[1][e] = __builtin_bit_cast(short, __float2bfloat16(c2[e]));
            W2a[1][4 + e] = __builtin_bit_cast(short, __float2bfloat16(c3[e]));
        }
    }
    // Biases for this lane's C-layout rows: chunk q -> rows 8q+4*l5..+3
    f32x4 b1v[4], b2v[4];
    #pragma unroll
    for (int q = 0; q < 4; ++q) {
        b1v[q] = *(const f32x4*)(b1 + 8 * q + 4 * l5);
        b2v[q] = *(const f32x4*)(b2 + 8 * q + 4 * l5);
    }

    const float* rbf_bn = rbf + (size_t)bn * (N_ * 32);
    const float* rij_bn = rij + (size_t)bn * (N_ * 3);
    const float* ten_b  = tensor + (size_t)b * (N_ * C_ * 3);

    // rbf B-fragments: lane col=edge k, k-dim 8*l5+e / 16+8*l5+e
    const float* ap = rbf_bn + (size_t)k * 32 + 8 * l5;
    const f32x4 x0 = ((const f32x4*)ap)[0];
    const f32x4 x1 = ((const f32x4*)ap)[1];
    const f32x4 x2 = ((const f32x4*)(ap + 16))[0];
    const f32x4 x3 = ((const f32x4*)(ap + 16))[1];
    const float rx = rij_bn[k * 3 + 0];
    const float ry = rij_bn[k * 3 + 1];
    const float rz = rij_bn[k * 3 + 2];
    const float* tp = ten_b + ((size_t)k * 32 + 4 * l5) * 3;

    bf16x8 X0, X1;
    #pragma unroll
    for (int e = 0; e < 4; ++e) {
        X0[e]     = __builtin_bit_cast(short, __float2bfloat16(x0[e]));
        X0[4 + e] = __builtin_bit_cast(short, __float2bfloat16(x1[e]));
        X1[e]     = __builtin_bit_cast(short, __float2bfloat16(x2[e]));
        X1[4 + e] = __builtin_bit_cast(short, __float2bfloat16(x3[e]));
    }

    // Layer 1 (K=32 via 2 MFMAs into one acc)
    f32x16 h;
    #pragma unroll
    for (int i = 0; i < 16; ++i) h[i] = 0.f;
    h = __builtin_amdgcn_mfma_f32_32x32x16_bf16(W1a[0], X0, h, 0, 0, 0);
    h = __builtin_amdgcn_mfma_f32_32x32x16_bf16(W1a[1], X1, h, 0, 0, 0);

    // bias + relu + pack (proven R6 path)
    unsigned pk0, pk1, pk2, pk3, pk4, pk5, pk6, pk7;
    {
        const float h0 = fmaxf(h[0] + b1v[0][0], 0.f), h1 = fmaxf(h[1] + b1v[0][1], 0.f);
        const float h2 = fmaxf(h[2] + b1v[0][2], 0.f), h3 = fmaxf(h[3] + b1v[0][3], 0.f);
        const float h4 = fmaxf(h[4] + b1v[1][0], 0.f), h5 = fmaxf(h[5] + b1v[1][1], 0.f);
        const float h6 = fmaxf(h[6] + b1v[1][2], 0.f), h7 = fmaxf(h[7] + b1v[1][3], 0.f);
        const float h8 = fmaxf(h[8] + b1v[2][0], 0.f), h9 = fmaxf(h[9] + b1v[2][1], 0.f);
        const float hA = fmaxf(h[10] + b1v[2][2], 0.f), hB = fmaxf(h[11] + b1v[2][3], 0.f);
        const float hC = fmaxf(h[12] + b1v[3][0], 0.f), hD = fmaxf(h[13] + b1v[3][1], 0.f);
        const float hE = fmaxf(h[14] + b1v[3][2], 0.f), hF = fmaxf(h[15] + b1v[3][3], 0.f);
        pk0 = pkbf(h0, h1); pk1 = pkbf(h2, h3);
        pk2 = pkbf(h4, h5); pk3 = pkbf(h6, h7);
        pk4 = pkbf(h8, h9); pk5 = pkbf(hA, hB);
        pk6 = pkbf(hC, hD); pk7 = pkbf(hE, hF);
    }
    const unsigned q0 = __shfl_xor(pk0, 32, 64);
    const unsigned q1 = __shfl_xor(pk1, 32, 64);
    const unsigned q2 = __shfl_xor(pk2, 32, 64);
    const unsigned q3 = __shfl_xor(pk3, 32, 64);
    const unsigned q4 = __shfl_xor(pk4, 32, 64);
    const unsigned q5 = __shfl_xor(pk5, 32, 64);
    const unsigned q6 = __shfl_xor(pk6, 32, 64);
    const unsigned q7 = __shfl_xor(pk7, 32, 64);
    const bool lo = (l5 == 0);
    const u32x4 f1d = { lo ? pk0 : q2, lo ? pk1 : q3, lo ? q0 : pk2, lo ? q1 : pk3 };
    const u32x4 f2d = { lo ? pk4 : q6, lo ? pk5 : q7, lo ? q4 : pk6, lo ? q5 : pk7 };
    const bf16x8 Hf1 = __builtin_bit_cast(bf16x8, f1d);
    const bf16x8 Hf2 = __builtin_bit_cast(bf16x8, f2d);

    // Layer 2
    f32x16 rr;
    #pragma unroll
    for (int i = 0; i < 16; ++i) rr[i] = 0.f;
    rr = __builtin_amdgcn_mfma_f32_32x32x16_bf16(W2a[0], Hf1, rr, 0, 0, 0);
    rr = __builtin_amdgcn_mfma_f32_32x32x16_bf16(W2a[1], Hf2, rr, 0, 0, 0);

    // Epilogue: lane's edge k, channel rows 8q+4l5+r
    const float r2v = rx * rx + ry * ry + rz * rz;
    const float inv = rsqrtf(fmaxf(r2v, 1e-8f));
    const float vm  = (r2v >= 1e-16f) ? 1.f : 0.f;   // |rij| >= 1e-8
    f32x16 c;
    #pragma unroll
    for (int q = 0; q < 4; ++q) {
        const f32x4 g0 = ((const f32x4*)(tp + 24 * q))[0];
        const f32x4 g1 = ((const f32x4*)(tp + 24 * q))[1];
        const f32x4 g2 = ((const f32x4*)(tp + 24 * q))[2];
        const float s0 = (rx * g0[0] + ry * g0[1] + rz * g0[2]) * inv;
        const float sv1 = (rx * g0[3] + ry * g1[0] + rz * g1[1]) * inv;
        const float sv2 = (rx * g1[2] + ry * g1[3] + rz * g2[0]) * inv;
        const float sv3 = (rx * g2[1] + ry * g2[2] + rz * g2[3]) * inv;
        c[4 * q + 0] = vm * (rr[4 * q + 0] + b2v[q][0]) * s0;
        c[4 * q + 1] = vm * (rr[4 * q + 1] + b2v[q][1]) * sv1;
        c[4 * q + 2] = vm * (rr[4 * q + 2] + b2v[q][2]) * sv2;
        c[4 * q + 3] = vm * (rr[4 * q + 3] + b2v[q][3]) * sv3;
    }

    // Butterfly-reduce over the 32 edge-columns (masks < 32: closed per half).
    #pragma unroll
    for (int i = 0; i < 16; ++i) {
        float v = c[i];
        #pragma unroll
        for (int m = 1; m <= 16; m <<= 1) v += __shfl_xor(v, m, 64);
        c[i] = v;
    }
    if (l == 0) {   // lanes 0 and 32 hold disjoint channel sets
        if constexpr (USE_WS) {
            float* o = dst + (size_t)T * 32;
            #pragma unroll
            for (int q = 0; q < 4; ++q)
                *reinterpret_cast<f32x4*>(o + 8 * q + 4 * l5) =
                    f32x4{ c[4 * q + 0], c[4 * q + 1], c[4 * q + 2], c[4 * q + 3] };
        } else {
            float* o = dst + (size_t)bn * 32;
            #pragma unroll
            for (int q = 0; q < 4; ++q)
                #pragma unroll
                for (int r = 0; r < 4; ++r)
                    atomicAdd(o + 8 * q + 4 * l5 + r, c[4 * q + r]);
        }
    }
}

// out[bn,ch] = sum_{t<16} ws[bn*16+t][ch]  (fixed order -> deterministic)
__global__ __launch_bounds__(256)
void reduce16(const float* __restrict__ ws, float* __restrict__ out) {
    const int i  = blockIdx.x * 256 + threadIdx.x;   // 32768 outputs
    const int bn = i >> 5, ch = i & 31;
    const float* p = ws + (size_t)bn * 512 + ch;
    float s = 0.f;
    #pragma unroll
    for (int t = 0; t < 16; ++t) s += p[t * 32];
    out[i] = s;
}

extern "C" void kernel_launch(void* const* d_in, const int* in_sizes, int n_in,
                              void* d_out, int out_size, void* d_ws, size_t ws_size,
                              hipStream_t stream) {
    const float* tensor = (const float*)d_in[0];
    const float* rbf    = (const float*)d_in[1];
    const float* rij    = (const float*)d_in[2];
    const float* W1     = (const float*)d_in[3];
    const float* b1     = (const float*)d_in[4];
    const float* W2     = (const float*)d_in[5];
    const float* b2     = (const float*)d_in[6];
    float* out = (float*)d_out;

    const size_t ws_need = (size_t)NTILES * 32 * sizeof(float);   // 2 MB
    dim3 block(256), grid(NTILES / 4);
    if (ws_size >= ws_need) {
        float* ws = (float*)d_ws;
        filter_tile<true><<<grid, block, 0, stream>>>(tensor, rbf, rij, W1, b1, W2, b2, ws);
        reduce16<<<dim3(32768 / 256), block, 0, stream>>>(ws, out);
    } else {
        hipMemsetAsync(out, 0, (size_t)out_size * sizeof(float), stream);
        filter_tile<false><<<grid, block, 0, stream>>>(tensor, rbf, rij, W1, b1, W2, b2, out);
    }
}

// Round 8
// 45.852 us; speedup vs baseline: 1.2164x; 1.2164x over previous
//
#include <hip/hip_runtime.h>
#include <hip/hip_bf16.h>

using bf16x8 = __attribute__((ext_vector_type(8))) short;
using f32x4  = __attribute__((ext_vector_type(4))) float;
using f32x16 = __attribute__((ext_vector_type(16))) float;
using u32x4  = __attribute__((ext_vector_type(4))) unsigned;

constexpr int N_ = 512;
constexpr int C_ = 32;

__device__ __forceinline__ unsigned pkbf(float lo, float hi) {
    unsigned a = (unsigned short)__builtin_bit_cast(short, __float2bfloat16(lo));
    unsigned b = (unsigned short)__builtin_bit_cast(short, __float2bfloat16(hi));
    return a | (b << 16);
}

// One block per bn row: 8 waves x 2 tiles (32 edges each) = 512 edges.
// Per-tile math identical to the R6/R7-proven 32x32 MFMA + shfl-relayout path.
// rbf for BOTH tiles prefetched to registers before tile-0 compute (L3 latency
// hides under tile-0 body). Butterfly + weight setup amortized over 2 tiles.
__global__ __launch_bounds__(512, 2)
void filter_t2(const float* __restrict__ tensor,  // [B,N,C,3]
               const float* __restrict__ rbf,     // [B,N,N,32]
               const float* __restrict__ rij,     // [B,N,N,3]
               const float* __restrict__ W1,
               const float* __restrict__ b1,
               const float* __restrict__ W2,
               const float* __restrict__ b2,
               float* __restrict__ out)            // [B,N,C]
{
    const int bn   = blockIdx.x;
    const int b    = bn >> 9;
    const int tid  = threadIdx.x;
    const int lane = tid & 63;
    const int w    = tid >> 6;    // wave 0..7
    const int l    = lane & 31;   // edge-in-tile / A-row / C-col
    const int l5   = lane >> 5;   // k-group (0,1)

    __shared__ float red[8][32];

    // Weight A-fragments: lane holds row m=l, k = 8*l5+e (frag0), 16+8*l5+e (frag1)
    bf16x8 W1a[2], W2a[2];
    {
        const float* p1 = W1 + l * 32 + 8 * l5;
        const float* p2 = W2 + l * 32 + 8 * l5;
        const f32x4 a0 = ((const f32x4*)p1)[0], a1 = ((const f32x4*)p1)[1];
        const f32x4 a2 = ((const f32x4*)(p1 + 16))[0], a3 = ((const f32x4*)(p1 + 16))[1];
        const f32x4 c0 = ((const f32x4*)p2)[0], c1 = ((const f32x4*)p2)[1];
        const f32x4 c2 = ((const f32x4*)(p2 + 16))[0], c3 = ((const f32x4*)(p2 + 16))[1];
        #pragma unroll
        for (int e = 0; e < 4; ++e) {
            W1a[0][e] = __builtin_bit_cast(short, __float2bfloat16(a0[e]));
            W1a[0][4 + e] = __builtin_bit_cast(short, __float2bfloat16(a1[e]));
            W1a[1][e] = __builtin_bit_cast(short, __float2bfloat16(a2[e]));
            W1a[1][4 + e] = __builtin_bit_cast(short, __float2bfloat16(a3[e]));
            W2a[0][e] = __builtin_bit_cast(short, __float2bfloat16(c0[e]));
            W2a[0][4 + e] = __builtin_bit_cast(short, __float2bfloat16(c1[e]));
            W2a[1][e] = __builtin_bit_cast(short, __float2bfloat16(c2[e]));
            W2a[1][4 + e] = __builtin_bit_cast(short, __float2bfloat16(c3[e]));
        }
    }

    const float* rbf_bn = rbf + (size_t)bn * (N_ * 32);
    const float* rij_bn = rij + (size_t)bn * (N_ * 3);
    const float* ten_b  = tensor + (size_t)b * (N_ * C_ * 3);

    // Prefetch BOTH tiles' rbf fragments + rij now; tile-1's L3 latency hides
    // under tile-0's compute. Kept compact: 4 bf16x8 frags (16 VGPR) + 6 f32.
    bf16x8 X0[2], X1[2];
    float rxv[2], ryv[2], rzv[2];
    #pragma unroll
    for (int t = 0; t < 2; ++t) {
        const int k = w * 64 + t * 32 + l;
        const float* ap = rbf_bn + (size_t)k * 32 + 8 * l5;
        const f32x4 x0 = ((const f32x4*)ap)[0];
        const f32x4 x1 = ((const f32x4*)ap)[1];
        const f32x4 x2 = ((const f32x4*)(ap + 16))[0];
        const f32x4 x3 = ((const f32x4*)(ap + 16))[1];
        #pragma unroll
        for (int e = 0; e < 4; ++e) {
            X0[t][e]     = __builtin_bit_cast(short, __float2bfloat16(x0[e]));
            X0[t][4 + e] = __builtin_bit_cast(short, __float2bfloat16(x1[e]));
            X1[t][e]     = __builtin_bit_cast(short, __float2bfloat16(x2[e]));
            X1[t][4 + e] = __builtin_bit_cast(short, __float2bfloat16(x3[e]));
        }
        rxv[t] = rij_bn[k * 3 + 0];
        ryv[t] = rij_bn[k * 3 + 1];
        rzv[t] = rij_bn[k * 3 + 2];
    }

    f32x16 accO;
    #pragma unroll
    for (int i = 0; i < 16; ++i) accO[i] = 0.f;

    #pragma unroll
    for (int t = 0; t < 2; ++t) {
        const int k = w * 64 + t * 32 + l;
        const float* tp = ten_b + ((size_t)k * 32 + 4 * l5) * 3;

        // Layer 1 (K=32 via 2 MFMAs into one acc)
        f32x16 h;
        #pragma unroll
        for (int i = 0; i < 16; ++i) h[i] = 0.f;
        h = __builtin_amdgcn_mfma_f32_32x32x16_bf16(W1a[0], X0[t], h, 0, 0, 0);
        h = __builtin_amdgcn_mfma_f32_32x32x16_bf16(W1a[1], X1[t], h, 0, 0, 0);

        // Lazy bias loads (L1-hit, transient registers).
        f32x4 b1v[4];
        #pragma unroll
        for (int q = 0; q < 4; ++q) b1v[q] = *(const f32x4*)(b1 + 8 * q + 4 * l5);

        // bias + relu + pack (proven path)
        unsigned pk0, pk1, pk2, pk3, pk4, pk5, pk6, pk7;
        {
            const float h0 = fmaxf(h[0] + b1v[0][0], 0.f), h1 = fmaxf(h[1] + b1v[0][1], 0.f);
            const float h2 = fmaxf(h[2] + b1v[0][2], 0.f), h3 = fmaxf(h[3] + b1v[0][3], 0.f);
            const float h4 = fmaxf(h[4] + b1v[1][0], 0.f), h5 = fmaxf(h[5] + b1v[1][1], 0.f);
            const float h6 = fmaxf(h[6] + b1v[1][2], 0.f), h7 = fmaxf(h[7] + b1v[1][3], 0.f);
            const float h8 = fmaxf(h[8] + b1v[2][0], 0.f), h9 = fmaxf(h[9] + b1v[2][1], 0.f);
            const float hA = fmaxf(h[10] + b1v[2][2], 0.f), hB = fmaxf(h[11] + b1v[2][3], 0.f);
            const float hC = fmaxf(h[12] + b1v[3][0], 0.f), hD = fmaxf(h[13] + b1v[3][1], 0.f);
            const float hE = fmaxf(h[14] + b1v[3][2], 0.f), hF = fmaxf(h[15] + b1v[3][3], 0.f);
            pk0 = pkbf(h0, h1); pk1 = pkbf(h2, h3);
            pk2 = pkbf(h4, h5); pk3 = pkbf(h6, h7);
            pk4 = pkbf(h8, h9); pk5 = pkbf(hA, hB);
            pk6 = pkbf(hC, hD); pk7 = pkbf(hE, hF);
        }
        const unsigned q0 = __shfl_xor(pk0, 32, 64);
        const unsigned q1 = __shfl_xor(pk1, 32, 64);
        const unsigned q2 = __shfl_xor(pk2, 32, 64);
        const unsigned q3 = __shfl_xor(pk3, 32, 64);
        const unsigned q4 = __shfl_xor(pk4, 32, 64);
        const unsigned q5 = __shfl_xor(pk5, 32, 64);
        const unsigned q6 = __shfl_xor(pk6, 32, 64);
        const unsigned q7 = __shfl_xor(pk7, 32, 64);
        const bool lo = (l5 == 0);
        const u32x4 f1d = { lo ? pk0 : q2, lo ? pk1 : q3, lo ? q0 : pk2, lo ? q1 : pk3 };
        const u32x4 f2d = { lo ? pk4 : q6, lo ? pk5 : q7, lo ? q4 : pk6, lo ? q5 : pk7 };
        const bf16x8 Hf1 = __builtin_bit_cast(bf16x8, f1d);
        const bf16x8 Hf2 = __builtin_bit_cast(bf16x8, f2d);

        // Layer 2
        f32x16 rr;
        #pragma unroll
        for (int i = 0; i < 16; ++i) rr[i] = 0.f;
        rr = __builtin_amdgcn_mfma_f32_32x32x16_bf16(W2a[0], Hf1, rr, 0, 0, 0);
        rr = __builtin_amdgcn_mfma_f32_32x32x16_bf16(W2a[1], Hf2, rr, 0, 0, 0);

        // Epilogue: lane's edge k, channel rows 8q+4l5+r
        const float rx = rxv[t], ry = ryv[t], rz = rzv[t];
        const float r2v = rx * rx + ry * ry + rz * rz;
        const float inv = rsqrtf(fmaxf(r2v, 1e-8f));
        const float vm  = (r2v >= 1e-16f) ? 1.f : 0.f;   // |rij| >= 1e-8
        #pragma unroll
        for (int q = 0; q < 4; ++q) {
            const f32x4 g0 = ((const f32x4*)(tp + 24 * q))[0];
            const f32x4 g1 = ((const f32x4*)(tp + 24 * q))[1];
            const f32x4 g2 = ((const f32x4*)(tp + 24 * q))[2];
            const f32x4 bq = *(const f32x4*)(b2 + 8 * q + 4 * l5);   // lazy, L1-hit
            const float s0 = (rx * g0[0] + ry * g0[1] + rz * g0[2]) * inv;
            const float sv1 = (rx * g0[3] + ry * g1[0] + rz * g1[1]) * inv;
            const float sv2 = (rx * g1[2] + ry * g1[3] + rz * g2[0]) * inv;
            const float sv3 = (rx * g2[1] + ry * g2[2] + rz * g2[3]) * inv;
            accO[4 * q + 0] += vm * (rr[4 * q + 0] + bq[0]) * s0;
            accO[4 * q + 1] += vm * (rr[4 * q + 1] + bq[1]) * sv1;
            accO[4 * q + 2] += vm * (rr[4 * q + 2] + bq[2]) * sv2;
            accO[4 * q + 3] += vm * (rr[4 * q + 3] + bq[3]) * sv3;
        }
    }

    // Butterfly-reduce over the 32 edge-columns (masks < 32: closed per half),
    // amortized over both tiles.
    #pragma unroll
    for (int i = 0; i < 16; ++i) {
        float v = accO[i];
        #pragma unroll
        for (int m = 1; m <= 16; m <<= 1) v += __shfl_xor(v, m, 64);
        accO[i] = v;
    }
    if (l == 0) {   // lanes 0 and 32 hold disjoint channel sets
        #pragma unroll
        for (int q = 0; q < 4; ++q) {
            red[w][8 * q + 4 * l5 + 0] = accO[4 * q + 0];
            red[w][8 * q + 4 * l5 + 1] = accO[4 * q + 1];
            red[w][8 * q + 4 * l5 + 2] = accO[4 * q + 2];
            red[w][8 * q + 4 * l5 + 3] = accO[4 * q + 3];
        }
    }
    __syncthreads();
    if (tid < 32) {
        float s = 0.f;
        #pragma unroll
        for (int ww = 0; ww < 8; ++ww) s += red[ww][tid];
        out[bn * C_ + tid] = s;
    }
}

extern "C" void kernel_launch(void* const* d_in, const int* in_sizes, int n_in,
                              void* d_out, int out_size, void* d_ws, size_t ws_size,
                              hipStream_t stream) {
    const float* tensor = (const float*)d_in[0];
    const float* rbf    = (const float*)d_in[1];
    const float* rij    = (const float*)d_in[2];
    const float* W1     = (const float*)d_in[3];
    const float* b1     = (const float*)d_in[4];
    const float* W2     = (const float*)d_in[5];
    const float* b2     = (const float*)d_in[6];
    float* out = (float*)d_out;

    dim3 grid(2 * N_), block(512);
    filter_t2<<<grid, block, 0, stream>>>(tensor, rbf, rij, W1, b1, W2, b2, out);
}

// Round 9
// 42.695 us; speedup vs baseline: 1.3063x; 1.0739x over previous
//
#include <hip/hip_runtime.h>
#include <hip/hip_bf16.h>

using bf16x8 = __attribute__((ext_vector_type(8))) short;
using f32x2  = __attribute__((ext_vector_type(2))) float;
using f32x4  = __attribute__((ext_vector_type(4))) float;
using f32x16 = __attribute__((ext_vector_type(16))) float;
using u32x4  = __attribute__((ext_vector_type(4))) unsigned;

constexpr int N_ = 512;

__device__ __forceinline__ unsigned pkbf(float lo, float hi) {
    unsigned a = (unsigned short)__builtin_bit_cast(short, __float2bfloat16(lo));
    unsigned b = (unsigned short)__builtin_bit_cast(short, __float2bfloat16(hi));
    return a | (b << 16);
}

// Factorized: out[m] = sum_l W2[m,l]*G[l,m] + b2[m]*sum_k S[k,m],
//   S[k,m] = (mask*inv*rij[k]) . T[b,k,m,:],  G = sum_k H[k,l]*S[k,m]  (K=512 MFMA!)
// Per tile (32 edges): H = mfma(A=rbf, B=W1^T) [2], relayout (proven half-swap),
// S computed per-lane directly in B-frag layout, G += mfma(A=Hfrag, B=Sfrag) [2].
// No butterfly, no per-tile epilogue; W2 applied once per wave at the end.
__global__ __launch_bounds__(256, 4)
void filter_G(const float* __restrict__ tensor,  // [B,N,C,3]
              const float* __restrict__ rbf,     // [B,N,N,32]
              const float* __restrict__ rij,     // [B,N,N,3]
              const float* __restrict__ W1,
              const float* __restrict__ b1,
              const float* __restrict__ W2,
              const float* __restrict__ b2,
              float* __restrict__ out)            // [B,N,C]
{
    const int bn   = blockIdx.x;
    const int b    = bn >> 9;
    const int tid  = threadIdx.x;
    const int lane = tid & 63;
    const int w    = tid >> 6;    // wave 0..3
    const int lam  = lane & 31;
    const int l5   = lane >> 5;

    __shared__ f32x2 uxy[N_];   // (vm*inv)*rij.xy
    __shared__ float uzs[N_];   // (vm*inv)*rij.z
    __shared__ float red[4][32];

    const float* rij_bn = rij + (size_t)bn * (N_ * 3);
    const float* rbf_bn = rbf + (size_t)bn * (N_ * 32);
    const float* ten_b  = tensor + (size_t)b * (N_ * 32 * 3);

    // ---- prologue: per-edge mask*invnorm folded into rij (once per block)
    #pragma unroll
    for (int t = 0; t < 2; ++t) {
        const int k = tid + t * 256;
        const float rx = rij_bn[3 * k + 0];
        const float ry = rij_bn[3 * k + 1];
        const float rz = rij_bn[3 * k + 2];
        const float r2 = rx * rx + ry * ry + rz * rz;
        const float inv = rsqrtf(fmaxf(r2, 1e-8f));
        const float sc = (r2 >= 1e-16f) ? inv : 0.f;   // |rij| >= 1e-8 mask
        uxy[k] = f32x2{rx * sc, ry * sc};
        uzs[k] = rz * sc;
    }

    // W1 as MFMA-B fragments: col=ch(lam), k=8*l5+e (frag0), 16+8*l5+e (frag1)
    bf16x8 W1b[2];
    {
        const float* p1 = W1 + lam * 32 + 8 * l5;
        const f32x4 a0 = ((const f32x4*)p1)[0], a1 = ((const f32x4*)p1)[1];
        const f32x4 a2 = ((const f32x4*)(p1 + 16))[0], a3 = ((const f32x4*)(p1 + 16))[1];
        #pragma unroll
        for (int e = 0; e < 4; ++e) {
            W1b[0][e]     = __builtin_bit_cast(short, __float2bfloat16(a0[e]));
            W1b[0][4 + e] = __builtin_bit_cast(short, __float2bfloat16(a1[e]));
            W1b[1][e]     = __builtin_bit_cast(short, __float2bfloat16(a2[e]));
            W1b[1][4 + e] = __builtin_bit_cast(short, __float2bfloat16(a3[e]));
        }
    }
    const float b1s = b1[lam];   // C-layout col IS the channel -> uniform scalar

    __syncthreads();

    f32x16 G;
    #pragma unroll
    for (int i = 0; i < 16; ++i) G[i] = 0.f;
    float ssum = 0.f;

    #pragma unroll 2
    for (int j = 0; j < 4; ++j) {
        const int e0 = (w * 4 + j) * 32;

        // H-path: rbf A-frags (row=edge e0+lam, k=8*l5+e / 16+8*l5+e)
        const float* ap = rbf_bn + (size_t)(e0 + lam) * 32 + 8 * l5;
        const f32x4 x0 = ((const f32x4*)ap)[0];
        const f32x4 x1 = ((const f32x4*)ap)[1];
        const f32x4 x2 = ((const f32x4*)(ap + 16))[0];
        const f32x4 x3 = ((const f32x4*)(ap + 16))[1];
        bf16x8 X0, X1;
        #pragma unroll
        for (int e = 0; e < 4; ++e) {
            X0[e]     = __builtin_bit_cast(short, __float2bfloat16(x0[e]));
            X0[4 + e] = __builtin_bit_cast(short, __float2bfloat16(x1[e]));
            X1[e]     = __builtin_bit_cast(short, __float2bfloat16(x2[e]));
            X1[4 + e] = __builtin_bit_cast(short, __float2bfloat16(x3[e]));
        }

        // S-path: lane (lam,l5) builds B-frags S[k][lam]; sub1 k=8*l5+e, sub2 +16
        const int kb = e0 + 8 * l5;
        float s[16];
        #pragma unroll
        for (int e = 0; e < 8; ++e) {
            const int k1 = kb + e;
            const int k2 = k1 + 16;
            const f32x2 u1 = uxy[k1]; const float z1 = uzs[k1];
            const f32x2 u2 = uxy[k2]; const float z2 = uzs[k2];
            const float* t1 = ten_b + ((size_t)k1 * 32 + lam) * 3;
            const float* t2 = ten_b + ((size_t)k2 * 32 + lam) * 3;
            s[e]     = u1[0] * t1[0] + u1[1] * t1[1] + z1 * t1[2];
            s[8 + e] = u2[0] * t2[0] + u2[1] * t2[1] + z2 * t2[2];
        }
        #pragma unroll
        for (int i = 0; i < 16; ++i) ssum += s[i];
        const u32x4 B1 = { pkbf(s[0], s[1]),  pkbf(s[2], s[3]),
                           pkbf(s[4], s[5]),  pkbf(s[6], s[7]) };
        const u32x4 B2 = { pkbf(s[8], s[9]),  pkbf(s[10], s[11]),
                           pkbf(s[12], s[13]), pkbf(s[14], s[15]) };

        // Layer 1: H[edge][ch] (K=32 via 2 MFMAs)
        f32x16 h;
        #pragma unroll
        for (int i = 0; i < 16; ++i) h[i] = 0.f;
        h = __builtin_amdgcn_mfma_f32_32x32x16_bf16(X0, W1b[0], h, 0, 0, 0);
        h = __builtin_amdgcn_mfma_f32_32x32x16_bf16(X1, W1b[1], h, 0, 0, 0);

        // bias + relu + pack pairs (reg r -> edge E(r)=(r&3)+8*(r>>2)+4*l5, ch lam)
        unsigned P0, P1, P2, P3, P4, P5, P6, P7;
        {
            const float t0 = fmaxf(h[0] + b1s, 0.f),  t1v = fmaxf(h[1] + b1s, 0.f);
            const float t2v = fmaxf(h[2] + b1s, 0.f), t3 = fmaxf(h[3] + b1s, 0.f);
            const float t4 = fmaxf(h[4] + b1s, 0.f),  t5 = fmaxf(h[5] + b1s, 0.f);
            const float t6 = fmaxf(h[6] + b1s, 0.f),  t7 = fmaxf(h[7] + b1s, 0.f);
            const float t8 = fmaxf(h[8] + b1s, 0.f),  t9 = fmaxf(h[9] + b1s, 0.f);
            const float tA = fmaxf(h[10] + b1s, 0.f), tB = fmaxf(h[11] + b1s, 0.f);
            const float tC = fmaxf(h[12] + b1s, 0.f), tD = fmaxf(h[13] + b1s, 0.f);
            const float tE = fmaxf(h[14] + b1s, 0.f), tF = fmaxf(h[15] + b1s, 0.f);
            P0 = pkbf(t0, t1v); P1 = pkbf(t2v, t3);
            P2 = pkbf(t4, t5);  P3 = pkbf(t6, t7);
            P4 = pkbf(t8, t9);  P5 = pkbf(tA, tB);
            P6 = pkbf(tC, tD);  P7 = pkbf(tE, tF);
        }
        // Proven half-swap: A-frag needs H[edge=8*l5+e][lam] (sub1), +16 (sub2)
        const unsigned Q0 = __shfl_xor(P0, 32, 64);
        const unsigned Q1 = __shfl_xor(P1, 32, 64);
        const unsigned Q2 = __shfl_xor(P2, 32, 64);
        const unsigned Q3 = __shfl_xor(P3, 32, 64);
        const unsigned Q4 = __shfl_xor(P4, 32, 64);
        const unsigned Q5 = __shfl_xor(P5, 32, 64);
        const unsigned Q6 = __shfl_xor(P6, 32, 64);
        const unsigned Q7 = __shfl_xor(P7, 32, 64);
        const bool lo = (l5 == 0);
        const u32x4 A1 = { lo ? P0 : Q2, lo ? P1 : Q3, lo ? Q0 : P2, lo ? Q1 : P3 };
        const u32x4 A2 = { lo ? P4 : Q6, lo ? P5 : Q7, lo ? Q4 : P6, lo ? Q5 : P7 };

        // G += H^T-tile . S-tile   (persistent accumulator, K accumulates)
        G = __builtin_amdgcn_mfma_f32_32x32x16_bf16(
                __builtin_bit_cast(bf16x8, A1), __builtin_bit_cast(bf16x8, B1), G, 0, 0, 0);
        G = __builtin_amdgcn_mfma_f32_32x32x16_bf16(
                __builtin_bit_cast(bf16x8, A2), __builtin_bit_cast(bf16x8, B2), G, 0, 0, 0);
    }

    // Epilogue: out[lam] = sum_l W2[lam,l]*G[l,lam] + b2[lam]*ssum
    // Lane holds G rows l = E(r) = (r&3)+8*(r>>2)+4*l5 -> 4 aligned f32x4 of W2 row.
    float p = 0.f;
    #pragma unroll
    for (int q = 0; q < 4; ++q) {
        const f32x4 wv = *(const f32x4*)(W2 + lam * 32 + 8 * q + 4 * l5);
        p += wv[0] * G[4 * q + 0] + wv[1] * G[4 * q + 1]
           + wv[2] * G[4 * q + 2] + wv[3] * G[4 * q + 3];
    }
    p    += __shfl_xor(p, 32, 64);      // combine l5 halves (disjoint l-rows)
    ssum += __shfl_xor(ssum, 32, 64);   // combine l5 halves (disjoint edges)
    const float o = p + b2[lam] * ssum;
    if (l5 == 0) red[w][lam] = o;
    __syncthreads();
    if (tid < 32)
        out[bn * 32 + tid] = red[0][tid] + red[1][tid] + red[2][tid] + red[3][tid];
}

extern "C" void kernel_launch(void* const* d_in, const int* in_sizes, int n_in,
                              void* d_out, int out_size, void* d_ws, size_t ws_size,
                              hipStream_t stream) {
    const float* tensor = (const float*)d_in[0];
    const float* rbf    = (const float*)d_in[1];
    const float* rij    = (const float*)d_in[2];
    const float* W1     = (const float*)d_in[3];
    const float* b1     = (const float*)d_in[4];
    const float* W2     = (const float*)d_in[5];
    const float* b2     = (const float*)d_in[6];
    float* out = (float*)d_out;

    dim3 grid(2 * N_), block(256);
    filter_G<<<grid, block, 0, stream>>>(tensor, rbf, rij, W1, b1, W2, b2, out);
}

// Round 10
// 28.930 us; speedup vs baseline: 1.9279x; 1.4758x over previous
//
#include <hip/hip_runtime.h>
#include <hip/hip_bf16.h>

using bf16x8 = __attribute__((ext_vector_type(8))) short;
using f32x4  = __attribute__((ext_vector_type(4))) float;
using f32x16 = __attribute__((ext_vector_type(16))) float;
using u32x4  = __attribute__((ext_vector_type(4))) unsigned;

constexpr int N_ = 512;

__device__ __forceinline__ unsigned pkbf(float lo, float hi) {
    unsigned a = (unsigned short)__builtin_bit_cast(short, __float2bfloat16(lo));
    unsigned b = (unsigned short)__builtin_bit_cast(short, __float2bfloat16(hi));
    return a | (b << 16);
}
__device__ __forceinline__ float bfhi2f(unsigned u) {        // hi bf16 -> f32
    return __builtin_bit_cast(float, u & 0xFFFF0000u);
}
__device__ __forceinline__ float bflo2f(unsigned u) {        // lo bf16 -> f32
    return __builtin_bit_cast(float, u << 16);
}
__device__ __forceinline__ void gl2lds16(const float* g, float* l) {
    __builtin_amdgcn_global_load_lds(
        (const __attribute__((address_space(1))) void*)g,
        (__attribute__((address_space(3))) void*)l, 16, 0, 0);
}

// R9 factorization + coalesced tensor staging:
//   out[m] = sum_l W2[m,l]*G[l,m] + b2[m]*sum_k S[k,m]
//   S[k,m] = u_k . T[b,k,m,:],  u_k = mask*rij/|rij|  (bf16-packed in LDS)
//   G = sum_k H[k,l]*S[k,m] accumulated by MFMA over K=512.
// Tensor tile (12KB/wave) staged via global_load_lds (coalesced, no VGPR cost),
// S gathered from LDS (conflict-free). rbf depth-1 register prefetch; counted
// vmcnt(4) keeps prefetch in flight across the stage fence.
__global__ __launch_bounds__(256, 4)
void filter_L(const float* __restrict__ tensor,  // [B,N,C,3]
              const float* __restrict__ rbf,     // [B,N,N,32]
              const float* __restrict__ rij,     // [B,N,N,3]
              const float* __restrict__ W1,
              const float* __restrict__ b1,
              const float* __restrict__ W2,
              const float* __restrict__ b2,
              float* __restrict__ out)            // [B,N,C]
{
    const int bn   = blockIdx.x;
    const int b    = bn >> 9;
    const int tid  = threadIdx.x;
    const int lane = tid & 63;
    const int w    = tid >> 6;    // wave 0..3
    const int lam  = lane & 31;
    const int l5   = lane >> 5;

    __shared__ float    Ts[4][3072];    // 48 KB: per-wave tensor tile [32edge][32ch][3]
    __shared__ unsigned upk[N_][2];     //  4 KB: bf16-packed u vectors
    __shared__ float    red[4][32];

    const float* rij_bn = rij + (size_t)bn * (N_ * 3);
    const float* rbf_bn = rbf + (size_t)bn * (N_ * 32);
    const float* ten_b  = tensor + (size_t)b * (N_ * 32 * 3);

    // ---- prologue: masked unit vectors, bf16-packed (once per block)
    #pragma unroll
    for (int t = 0; t < 2; ++t) {
        const int k = tid + t * 256;
        const float rx = rij_bn[3 * k + 0];
        const float ry = rij_bn[3 * k + 1];
        const float rz = rij_bn[3 * k + 2];
        const float r2 = rx * rx + ry * ry + rz * rz;
        const float inv = rsqrtf(fmaxf(r2, 1e-8f));
        const float sc = (r2 >= 1e-16f) ? inv : 0.f;   // |rij| >= 1e-8 mask
        upk[k][0] = pkbf(rx * sc, ry * sc);
        upk[k][1] = pkbf(rz * sc, 0.f);
    }

    // W1 as MFMA-B fragments: col=ch(lam), k=8*l5+e (frag0), 16+8*l5+e (frag1)
    bf16x8 W1b[2];
    {
        const float* p1 = W1 + lam * 32 + 8 * l5;
        const f32x4 a0 = ((const f32x4*)p1)[0], a1 = ((const f32x4*)p1)[1];
        const f32x4 a2 = ((const f32x4*)(p1 + 16))[0], a3 = ((const f32x4*)(p1 + 16))[1];
        #pragma unroll
        for (int e = 0; e < 4; ++e) {
            W1b[0][e]     = __builtin_bit_cast(short, __float2bfloat16(a0[e]));
            W1b[0][4 + e] = __builtin_bit_cast(short, __float2bfloat16(a1[e]));
            W1b[1][e]     = __builtin_bit_cast(short, __float2bfloat16(a2[e]));
            W1b[1][4 + e] = __builtin_bit_cast(short, __float2bfloat16(a3[e]));
        }
    }
    const float b1s = b1[lam];

    __syncthreads();

    float* tsw = &Ts[w][0];

    // rbf raw prefetch (tile 0) FIRST, then stage tensor tile 0 (so the rbf
    // consume-wait leaves the gl_lds queue running).
    f32x4 xa[2], xb[2], xc[2], xd[2];
    {
        const float* ap = rbf_bn + (size_t)(w * 4 * 32 + lam) * 32 + 8 * l5;
        xa[0] = ((const f32x4*)ap)[0];
        xb[0] = ((const f32x4*)ap)[1];
        xc[0] = ((const f32x4*)(ap + 16))[0];
        xd[0] = ((const f32x4*)(ap + 16))[1];
    }
    {
        const float* gsrc = ten_b + (size_t)(w * 4 * 32) * 96;
        #pragma unroll
        for (int it = 0; it < 12; ++it)
            gl2lds16(gsrc + it * 256 + lane * 4, tsw + it * 256);
    }

    f32x16 G;
    #pragma unroll
    for (int i = 0; i < 16; ++i) G[i] = 0.f;
    float ssum = 0.f;

    #pragma unroll
    for (int j = 0; j < 4; ++j) {
        const int e0  = (w * 4 + j) * 32;
        const int cur = j & 1, nx = cur ^ 1;

        // cvt current rbf regs -> B-frag... (A-operand of H-MFMA, row=edge)
        bf16x8 X0, X1;
        #pragma unroll
        for (int e = 0; e < 4; ++e) {
            X0[e]     = __builtin_bit_cast(short, __float2bfloat16(xa[cur][e]));
            X0[4 + e] = __builtin_bit_cast(short, __float2bfloat16(xb[cur][e]));
            X1[e]     = __builtin_bit_cast(short, __float2bfloat16(xc[cur][e]));
            X1[4 + e] = __builtin_bit_cast(short, __float2bfloat16(xd[cur][e]));
        }
        // depth-1 rbf prefetch for next tile (stays in flight across vmcnt(4))
        if (j < 3) {
            const float* ap = rbf_bn + (size_t)(e0 + 32 + lam) * 32 + 8 * l5;
            xa[nx] = ((const f32x4*)ap)[0];
            xb[nx] = ((const f32x4*)ap)[1];
            xc[nx] = ((const f32x4*)(ap + 16))[0];
            xd[nx] = ((const f32x4*)(ap + 16))[1];
        }

        // Layer 1: H[edge][ch]
        f32x16 h;
        #pragma unroll
        for (int i = 0; i < 16; ++i) h[i] = 0.f;
        h = __builtin_amdgcn_mfma_f32_32x32x16_bf16(X0, W1b[0], h, 0, 0, 0);
        h = __builtin_amdgcn_mfma_f32_32x32x16_bf16(X1, W1b[1], h, 0, 0, 0);

        // bias + relu + pack pairs (reg r -> edge (r&3)+8*(r>>2)+4*l5, ch lam)
        unsigned P0, P1, P2, P3, P4, P5, P6, P7;
        {
            const float t0 = fmaxf(h[0] + b1s, 0.f),  t1v = fmaxf(h[1] + b1s, 0.f);
            const float t2v = fmaxf(h[2] + b1s, 0.f), t3 = fmaxf(h[3] + b1s, 0.f);
            const float t4 = fmaxf(h[4] + b1s, 0.f),  t5 = fmaxf(h[5] + b1s, 0.f);
            const float t6 = fmaxf(h[6] + b1s, 0.f),  t7 = fmaxf(h[7] + b1s, 0.f);
            const float t8 = fmaxf(h[8] + b1s, 0.f),  t9 = fmaxf(h[9] + b1s, 0.f);
            const float tA = fmaxf(h[10] + b1s, 0.f), tB = fmaxf(h[11] + b1s, 0.f);
            const float tC = fmaxf(h[12] + b1s, 0.f), tD = fmaxf(h[13] + b1s, 0.f);
            const float tE = fmaxf(h[14] + b1s, 0.f), tF = fmaxf(h[15] + b1s, 0.f);
            P0 = pkbf(t0, t1v); P1 = pkbf(t2v, t3);
            P2 = pkbf(t4, t5);  P3 = pkbf(t6, t7);
            P4 = pkbf(t8, t9);  P5 = pkbf(tA, tB);
            P6 = pkbf(tC, tD);  P7 = pkbf(tE, tF);
        }
        // proven half-swap -> A-frags (k-dim = edge)
        const unsigned Q0 = __shfl_xor(P0, 32, 64);
        const unsigned Q1 = __shfl_xor(P1, 32, 64);
        const unsigned Q2 = __shfl_xor(P2, 32, 64);
        const unsigned Q3 = __shfl_xor(P3, 32, 64);
        const unsigned Q4 = __shfl_xor(P4, 32, 64);
        const unsigned Q5 = __shfl_xor(P5, 32, 64);
        const unsigned Q6 = __shfl_xor(P6, 32, 64);
        const unsigned Q7 = __shfl_xor(P7, 32, 64);
        const bool lo = (l5 == 0);
        const u32x4 A1 = { lo ? P0 : Q2, lo ? P1 : Q3, lo ? Q0 : P2, lo ? Q1 : P3 };
        const u32x4 A2 = { lo ? P4 : Q6, lo ? P5 : Q7, lo ? Q4 : P6, lo ? Q5 : P7 };

        // Tensor tile j has landed (12 gl_lds); rbf prefetch (4) stays in flight.
        if (j < 3) asm volatile("s_waitcnt vmcnt(4)" ::: "memory");
        else       asm volatile("s_waitcnt vmcnt(0)" ::: "memory");

        // S-path from LDS: lane (lam,l5) builds B-frag dwords for its 16 k's.
        u32x4 B1d, B2d;
        float sp;
        #pragma unroll
        for (int e = 0; e < 8; ++e) {
            const int kl = 8 * l5 + e;
            const unsigned u0 = upk[e0 + kl][0], u1 = upk[e0 + kl][1];
            const float* tq = tsw + kl * 96 + 3 * lam;
            const float s = bflo2f(u0) * tq[0] + bfhi2f(u0) * tq[1] + bflo2f(u1) * tq[2];
            ssum += s;
            if (e & 1) B1d[e >> 1] = pkbf(sp, s); else sp = s;
        }
        #pragma unroll
        for (int e = 0; e < 8; ++e) {
            const int kl = 16 + 8 * l5 + e;
            const unsigned u0 = upk[e0 + kl][0], u1 = upk[e0 + kl][1];
            const float* tq = tsw + kl * 96 + 3 * lam;
            const float s = bflo2f(u0) * tq[0] + bfhi2f(u0) * tq[1] + bflo2f(u1) * tq[2];
            ssum += s;
            if (e & 1) B2d[e >> 1] = pkbf(sp, s); else sp = s;
        }

        // LDS reads done -> safe to overwrite tile; stage next tile now so its
        // latency hides under the G-MFMAs and next iteration's H-path.
        asm volatile("s_waitcnt lgkmcnt(0)" ::: "memory");
        if (j < 3) {
            const float* gsrc = ten_b + (size_t)(e0 + 32) * 96;
            #pragma unroll
            for (int it = 0; it < 12; ++it)
                gl2lds16(gsrc + it * 256 + lane * 4, tsw + it * 256);
        }

        G = __builtin_amdgcn_mfma_f32_32x32x16_bf16(
                __builtin_bit_cast(bf16x8, A1), __builtin_bit_cast(bf16x8, B1d), G, 0, 0, 0);
        G = __builtin_amdgcn_mfma_f32_32x32x16_bf16(
                __builtin_bit_cast(bf16x8, A2), __builtin_bit_cast(bf16x8, B2d), G, 0, 0, 0);
    }

    // Epilogue (R9-proven): out[lam] = sum_l W2[lam,l]*G[l,lam] + b2[lam]*ssum
    float p = 0.f;
    #pragma unroll
    for (int q = 0; q < 4; ++q) {
        const f32x4 wv = *(const f32x4*)(W2 + lam * 32 + 8 * q + 4 * l5);
        p += wv[0] * G[4 * q + 0] + wv[1] * G[4 * q + 1]
           + wv[2] * G[4 * q + 2] + wv[3] * G[4 * q + 3];
    }
    p    += __shfl_xor(p, 32, 64);
    ssum += __shfl_xor(ssum, 32, 64);
    const float o = p + b2[lam] * ssum;
    if (l5 == 0) red[w][lam] = o;
    __syncthreads();
    if (tid < 32)
        out[bn * 32 + tid] = red[0][tid] + red[1][tid] + red[2][tid] + red[3][tid];
}

extern "C" void kernel_launch(void* const* d_in, const int* in_sizes, int n_in,
                              void* d_out, int out_size, void* d_ws, size_t ws_size,
                              hipStream_t stream) {
    const float* tensor = (const float*)d_in[0];
    const float* rbf    = (const float*)d_in[1];
    const float* rij    = (const float*)d_in[2];
    const float* W1     = (const float*)d_in[3];
    const float* b1     = (const float*)d_in[4];
    const float* W2     = (const float*)d_in[5];
    const float* b2     = (const float*)d_in[6];
    float* out = (float*)d_out;

    dim3 grid(2 * N_), block(256);
    filter_L<<<grid, block, 0, stream>>>(tensor, rbf, rij, W1, b1, W2, b2, out);
}